// Round 1
// baseline (47.010 us; speedup 1.0000x reference)
//
#include <hip/hip_runtime.h>
#include <math.h>

#define TT 512
#define DD 256
#define BIGF 9999.0f
#define KK 8

struct Ws {
  float a[TT];
  float b[TT];
  unsigned long long mb[TT][4];
};

__global__ __launch_bounds__(256) void prep_kernel(
    const float* __restrict__ X, const float* __restrict__ H,
    const float* __restrict__ C, const int* __restrict__ M,
    float* __restrict__ out, Ws* __restrict__ ws) {
  const int i = blockIdx.x;
  const int d = threadIdx.x;
  const int idx = i * DD + d;
  const float x = X[idx], h = H[idx], c = C[idx];
  const int m = M[idx];
  const float e = m ? (x - h + c) : 0.0f;
  float pm = e * e;
  float ph = h;
  float ph2 = h * h;
#pragma unroll
  for (int s = 1; s < 64; s <<= 1) {
    pm  += __shfl_xor(pm, s);
    ph  += __shfl_xor(ph, s);
    ph2 += __shfl_xor(ph2, s);
  }
  unsigned long long bal = __ballot(m != 0);
  __shared__ float sm[4], sh[4], sh2[4];
  const int wid = threadIdx.x >> 6;
  const int lane = threadIdx.x & 63;
  if (lane == 0) {
    sm[wid] = pm; sh[wid] = ph; sh2[wid] = ph2;
    ws->mb[i][wid] = bal;
  }
  __syncthreads();
  if (threadIdx.x == 0) {
    ws->a[i] = sh[0] + sh[1] + sh[2] + sh[3];
    ws->b[i] = sh2[0] + sh2[1] + sh2[2] + sh2[3];
    atomicAdd(out, sm[0] + sm[1] + sm[2] + sm[3]);
  }
}

// One block handles 4 consecutive i-rows; thread t owns column j = t.
__global__ __launch_bounds__(512) void score_kernel(
    const float* __restrict__ H, float* __restrict__ out,
    const Ws* __restrict__ ws) {
  __shared__ float Hi[4][DD];     // 4 KB
  __shared__ float sc[4][TT];     // 8 KB  (scores)
  __shared__ float nr[4][TT];     // 8 KB  (norms = sqrt(s2))

  const int i0 = blockIdx.x * 4;
  const int t = threadIdx.x;

  // stage the 4 i-rows (coalesced)
  for (int q = t; q < 4 * DD; q += 512) {
    const int r = q >> 8, d = q & (DD - 1);
    Hi[r][d] = H[(i0 + r) * DD + d];
  }
  __syncthreads();

  const int j = t;
  const float* __restrict__ hj = H + (size_t)j * DD;
  float acc0 = 0.f, acc1 = 0.f, acc2 = 0.f, acc3 = 0.f;
#pragma unroll 4
  for (int d = 0; d < DD; d += 4) {
    const float4 hv = *(const float4*)(hj + d);
    float4 h0 = *(const float4*)&Hi[0][d];
    float4 h1 = *(const float4*)&Hi[1][d];
    float4 h2 = *(const float4*)&Hi[2][d];
    float4 h3 = *(const float4*)&Hi[3][d];
    acc0 += hv.x * h0.x + hv.y * h0.y + hv.z * h0.z + hv.w * h0.w;
    acc1 += hv.x * h1.x + hv.y * h1.y + hv.z * h1.z + hv.w * h1.w;
    acc2 += hv.x * h2.x + hv.y * h2.y + hv.z * h2.z + hv.w * h2.w;
    acc3 += hv.x * h3.x + hv.y * h3.y + hv.z * h3.z + hv.w * h3.w;
  }

  const float aj = ws->a[j];
  const float bj = ws->b[j];
  const unsigned long long mj0 = ws->mb[j][0], mj1 = ws->mb[j][1],
                           mj2 = ws->mb[j][2], mj3 = ws->mb[j][3];
  const float accs[4] = {acc0, acc1, acc2, acc3};
#pragma unroll
  for (int r = 0; r < 4; ++r) {
    const int i = i0 + r;
    const float ai = ws->a[i];
    const float bi = ws->b[i];
    const float s2 = bi + bj - 2.0f * accs[r];
    const float s1 = ai - aj;
    const float var = (s2 - s1 * s1 * (1.0f / DD)) * (1.0f / (DD - 1));
    const bool diff = (mj0 != ws->mb[i][0]) | (mj1 != ws->mb[i][1]) |
                      (mj2 != ws->mb[i][2]) | (mj3 != ws->mb[i][3]);
    const bool valid = diff && (j != i);
    sc[r][j] = valid ? sqrtf(fmaxf(var, 0.0f)) : BIGF;
    nr[r][j] = sqrtf(fmaxf(s2, 0.0f));
  }
  __syncthreads();

  // one wave per row: iterative top-8 smallest with lowest-index tie-break
  const int wid = t >> 6;
  const int lane = t & 63;
  if (wid < 4) {
    const int r = wid;
    float cv[8];
#pragma unroll
    for (int c = 0; c < 8; ++c) cv[c] = sc[r][lane + 64 * c];

    float kv[KK];
    int ki[KK];
#pragma unroll
    for (int k = 0; k < KK; ++k) {
      // local argmin over the 8 register candidates (lowest index wins ties)
      float bv = cv[0];
      int bc = 0;
#pragma unroll
      for (int c = 1; c < 8; ++c) {
        if (cv[c] < bv) { bv = cv[c]; bc = c; }
      }
      int bidx = lane + 64 * bc;
      // wave argmin, lexicographic (val, idx)
#pragma unroll
      for (int s = 1; s < 64; s <<= 1) {
        const float ov = __shfl_xor(bv, s);
        const int oi = __shfl_xor(bidx, s);
        if (ov < bv || (ov == bv && oi < bidx)) { bv = ov; bidx = oi; }
      }
      kv[k] = bv;
      ki[k] = bidx;
      // consume the winner (static indexing only)
      const int csel = bidx >> 6;
      const bool mine = (bidx & 63) == lane;
#pragma unroll
      for (int c = 0; c < 8; ++c) {
        if (mine && c == csel) cv[c] = BIGF;
      }
    }
    // softmax over -kv (kv ascending, so kv[0] is the max of -kv)
    float wsum = 0.0f;
    float wv[KK];
#pragma unroll
    for (int k = 0; k < KK; ++k) {
      wv[k] = expf(kv[0] - kv[k]);
      wsum += wv[k];
    }
    float rl = 0.0f;
#pragma unroll
    for (int k = 0; k < KK; ++k) {
      rl += wv[k] * nr[r][ki[k]];
    }
    rl /= wsum;
    if (lane == 0) atomicAdd(out, rl);
  }
}

extern "C" void kernel_launch(void* const* d_in, const int* in_sizes, int n_in,
                              void* d_out, int out_size, void* d_ws, size_t ws_size,
                              hipStream_t stream) {
  const float* X = (const float*)d_in[0];
  const float* H = (const float*)d_in[1];
  const float* C = (const float*)d_in[2];
  const int* M = (const int*)d_in[3];
  float* out = (float*)d_out;
  Ws* ws = (Ws*)d_ws;

  hipMemsetAsync(d_out, 0, sizeof(float), stream);
  prep_kernel<<<TT, DD, 0, stream>>>(X, H, C, M, out, ws);
  score_kernel<<<TT / 4, 512, 0, stream>>>(H, out, ws);
}

// Round 2
// 35.779 us; speedup vs baseline: 1.3139x; 1.3139x over previous
//
#include <hip/hip_runtime.h>
#include <math.h>

#define TT 512
#define DD 256
#define BIGF 9999.0f
#define KK 8

// ws layout (bytes):
//   [0)        float ht[DD][TT]      512 KB   transposed H
//   [+524288)  float a[TT]           2 KB     row sums of H
//   [+526336)  float b[TT]           2 KB     row sums of H^2
//   [+528384)  ull   mb[TT][4]       16 KB    bit-packed mask rows
//   [+544768)  float msep[TT]        2 KB     per-row masked MSE partials
//   [+546816)  float rloss[TT]       2 KB     per-row weighted-norm losses
#define HT_OFF    0
#define A_OFF     524288
#define B_OFF     526336
#define MB_OFF    528384
#define MSEP_OFF  544768
#define RLOSS_OFF 546816

__global__ __launch_bounds__(256) void prep_kernel(
    const float* __restrict__ X, const float* __restrict__ H,
    const float* __restrict__ C, const int* __restrict__ M,
    float* __restrict__ ht, float* __restrict__ A, float* __restrict__ B,
    unsigned long long* __restrict__ MB, float* __restrict__ MSEP) {
  const int i = blockIdx.x;
  const int d = threadIdx.x;
  const int idx = i * DD + d;
  const float x = X[idx], h = H[idx], c = C[idx];
  const int m = M[idx];
  ht[d * TT + i] = h;  // transpose write (scattered, L2-absorbed, once)
  const float e = m ? (x - h + c) : 0.0f;
  float pm = e * e;
  float ph = h;
  float ph2 = h * h;
#pragma unroll
  for (int s = 1; s < 64; s <<= 1) {
    pm  += __shfl_xor(pm, s);
    ph  += __shfl_xor(ph, s);
    ph2 += __shfl_xor(ph2, s);
  }
  const unsigned long long bal = __ballot(m != 0);
  __shared__ float sm[4], sh[4], sh2[4];
  const int wid = d >> 6, lane = d & 63;
  if (lane == 0) {
    sm[wid] = pm; sh[wid] = ph; sh2[wid] = ph2;
    MB[i * 4 + wid] = bal;
  }
  __syncthreads();
  if (d == 0) {
    A[i] = sh[0] + sh[1] + sh[2] + sh[3];
    B[i] = sh2[0] + sh2[1] + sh2[2] + sh2[3];
    MSEP[i] = sm[0] + sm[1] + sm[2] + sm[3];
  }
}

// Block = 4 i-rows x all 512 j. 256 threads; thread t owns j = {2t, 2t+1}.
// Register-tiled outer product over transposed H: no LDS in the hot loop,
// no cross-lane reduction, coalesced j-loads, uniform (1-line) i-loads.
__global__ __launch_bounds__(256) void score_kernel(
    const float* __restrict__ ht, const float* __restrict__ A,
    const float* __restrict__ B, const unsigned long long* __restrict__ MB,
    float* __restrict__ RLOSS) {
  __shared__ float dl[4][TT];   // scores
  __shared__ float nrm[4][TT];  // norms
  const int i0 = blockIdx.x * 4;
  const int t = threadIdx.x;

  float acc[4][2] = {{0.f, 0.f}, {0.f, 0.f}, {0.f, 0.f}, {0.f, 0.f}};
#pragma unroll 8
  for (int d = 0; d < DD; ++d) {
    const float4 hi = *(const float4*)(ht + d * TT + i0);      // uniform
    const float2 hj = *(const float2*)(ht + d * TT + 2 * t);   // coalesced
    acc[0][0] += hi.x * hj.x; acc[0][1] += hi.x * hj.y;
    acc[1][0] += hi.y * hj.x; acc[1][1] += hi.y * hj.y;
    acc[2][0] += hi.z * hj.x; acc[2][1] += hi.z * hj.y;
    acc[3][0] += hi.w * hj.x; acc[3][1] += hi.w * hj.y;
  }

  float ai[4], bi[4];
  unsigned long long mbi[4][4];
#pragma unroll
  for (int r = 0; r < 4; ++r) {
    ai[r] = A[i0 + r];
    bi[r] = B[i0 + r];
#pragma unroll
    for (int c = 0; c < 4; ++c) mbi[r][c] = MB[(i0 + r) * 4 + c];
  }

#pragma unroll
  for (int jj = 0; jj < 2; ++jj) {
    const int j = 2 * t + jj;
    const float aj = A[j], bj = B[j];
    const unsigned long long m0 = MB[j * 4 + 0], m1 = MB[j * 4 + 1],
                             m2 = MB[j * 4 + 2], m3 = MB[j * 4 + 3];
#pragma unroll
    for (int r = 0; r < 4; ++r) {
      const float dot = acc[r][jj];
      const float s2 = bi[r] + bj - 2.0f * dot;
      const float s1 = ai[r] - aj;
      const float var = (s2 - s1 * s1 * (1.0f / DD)) * (1.0f / (DD - 1));
      const bool diff = (m0 != mbi[r][0]) | (m1 != mbi[r][1]) |
                        (m2 != mbi[r][2]) | (m3 != mbi[r][3]);
      const bool valid = diff && (j != i0 + r);
      dl[r][j] = valid ? sqrtf(fmaxf(var, 0.0f)) : BIGF;
      nrm[r][j] = sqrtf(fmaxf(s2, 0.0f));
    }
  }
  __syncthreads();

  // wave w handles row i0+w: iterative top-8 smallest, lowest-index tie-break
  const int w = t >> 6, lane = t & 63;
  float cv[8];
#pragma unroll
  for (int c = 0; c < 8; ++c) cv[c] = dl[w][lane + 64 * c];

  float kv[KK];
  int ki[KK];
#pragma unroll
  for (int k = 0; k < KK; ++k) {
    float bv = cv[0];
    int bc = 0;
#pragma unroll
    for (int c = 1; c < 8; ++c) {
      if (cv[c] < bv) { bv = cv[c]; bc = c; }
    }
    int bidx = lane + 64 * bc;
#pragma unroll
    for (int s = 1; s < 64; s <<= 1) {
      const float ov = __shfl_xor(bv, s);
      const int oi = __shfl_xor(bidx, s);
      if (ov < bv || (ov == bv && oi < bidx)) { bv = ov; bidx = oi; }
    }
    kv[k] = bv;
    ki[k] = bidx;
    const int csel = bidx >> 6;
    const bool mine = (bidx & 63) == lane;
#pragma unroll
    for (int c = 0; c < 8; ++c) {
      if (mine && c == csel) cv[c] = BIGF;
    }
  }
  float wsum = 0.0f, rl = 0.0f;
#pragma unroll
  for (int k = 0; k < KK; ++k) {
    const float e = expf(kv[0] - kv[k]);  // kv[0] = min score = softmax max
    wsum += e;
    rl += e * nrm[w][ki[k]];
  }
  if (lane == 0) RLOSS[i0 + w] = rl / wsum;
}

__global__ __launch_bounds__(512) void finalize_kernel(
    const float* __restrict__ MSEP, const float* __restrict__ RLOSS,
    float* __restrict__ out) {
  const int t = threadIdx.x;
  float v = MSEP[t] + RLOSS[t];
#pragma unroll
  for (int s = 1; s < 64; s <<= 1) v += __shfl_xor(v, s);
  __shared__ float sp[8];
  if ((t & 63) == 0) sp[t >> 6] = v;
  __syncthreads();
  if (t == 0) {
    float r = 0.0f;
#pragma unroll
    for (int c = 0; c < 8; ++c) r += sp[c];
    out[0] = r;
  }
}

extern "C" void kernel_launch(void* const* d_in, const int* in_sizes, int n_in,
                              void* d_out, int out_size, void* d_ws, size_t ws_size,
                              hipStream_t stream) {
  const float* X = (const float*)d_in[0];
  const float* H = (const float*)d_in[1];
  const float* C = (const float*)d_in[2];
  const int* M = (const int*)d_in[3];
  float* out = (float*)d_out;

  char* ws = (char*)d_ws;
  float* ht = (float*)(ws + HT_OFF);
  float* A = (float*)(ws + A_OFF);
  float* B = (float*)(ws + B_OFF);
  unsigned long long* MB = (unsigned long long*)(ws + MB_OFF);
  float* MSEP = (float*)(ws + MSEP_OFF);
  float* RLOSS = (float*)(ws + RLOSS_OFF);

  prep_kernel<<<TT, DD, 0, stream>>>(X, H, C, M, ht, A, B, MB, MSEP);
  score_kernel<<<TT / 4, 256, 0, stream>>>(ht, A, B, MB, RLOSS);
  finalize_kernel<<<1, TT, 0, stream>>>(MSEP, RLOSS, out);
}